// Round 8
// baseline (164.109 us; speedup 1.0000x reference)
//
#include <hip/hip_runtime.h>
#include <hip/hip_bf16.h>
#include <cstdint>
#include <cstddef>

// MoE FFN: x[2,2048,1024] fp32, 8 experts top-2 + 1 shared expert.
// R1: no-atomic routing (ballot-based slot sort).
// R2: shared expert fused as expert #8 into grouped GEMMs.
// R3: LDS swizzle (bank conflicts -> 0).
// R6: 256x256 8-wave 8-phase GEMM.
// R7 (failed): staging map broke global_load_lds lane*16B contiguity + A-quadrant
//     write-before-read race.
// R8: quadrant-granular staging (1 load/thread/call, dest = uniform + lane*16B),
//     calendar respecting region lifetimes: ph2 A-q0, ph3 B-h0, ph4 A-q1+B-h1
//     +VMCNT(8); two barriers/phase, lgkmcnt(0)+sched_barrier before MFMA clusters.

#define NTOK 4096
#define DM 1024
#define DH 1024
#define NE 8
#define MAXSLOT_E 10240           // 8192 assignments + 8*256 padding (worst case)
#define MAXSLOT_ALL (MAXSLOT_E + NTOK)  // + shared segment (4096) = 14336
#define NASSIGN (NTOK * 2)
#define NRT2 (MAXSLOT_ALL / 256)  // 56 row tiles
#define GRID_G (NRT2 * 4)         // 224 blocks (4 col tiles)

typedef __attribute__((ext_vector_type(8))) short short8;
typedef __attribute__((ext_vector_type(8))) unsigned short ushort8v;
typedef __attribute__((ext_vector_type(4))) float f32x4;

__device__ __forceinline__ unsigned short f2bf(float f) {
  uint32_t u = __float_as_uint(f);
  return (unsigned short)((u + 0x7FFFu + ((u >> 16) & 1u)) >> 16);  // RNE
}
__device__ __forceinline__ float bf2f(unsigned short h) {
  return __uint_as_float(((uint32_t)h) << 16);
}

__device__ __forceinline__ void async_ld16(const void* g, void* l) {
  __builtin_amdgcn_global_load_lds(
      (const __attribute__((address_space(1))) void*)g,
      (__attribute__((address_space(3))) void*)l, 16, 0, 0);
}

__device__ __forceinline__ void BARR() {
  asm volatile("" ::: "memory");
  __builtin_amdgcn_s_barrier();
  asm volatile("" ::: "memory");
}
__device__ __forceinline__ void LGKM0() {
  asm volatile("s_waitcnt lgkmcnt(0)" ::: "memory");
  __builtin_amdgcn_sched_barrier(0);
}
#define VMCNT(n) asm volatile("s_waitcnt vmcnt(" #n ")" ::: "memory")

// ---------------- fp32 -> bf16 convert (no transpose) ----------------
__global__ __launch_bounds__(256) void k_cvt(const float* __restrict__ s,
                                             unsigned short* __restrict__ d, int n) {
  int i = (blockIdx.x * 256 + threadIdx.x) * 4;
  if (i >= n) return;
  float4 v = *(const float4*)(s + i);
  ushort4 o;
  o.x = f2bf(v.x); o.y = f2bf(v.y); o.z = f2bf(v.z); o.w = f2bf(v.w);
  *(ushort4*)(d + i) = o;
}

// ------------- fp32 [1024][1024] -> bf16 transposed [1024][1024] -------------
__global__ __launch_bounds__(256) void k_tcvt(const float* __restrict__ src,
                                              unsigned short* __restrict__ dst) {
  __shared__ float tile[64][65];
  const float* S = src + (size_t)blockIdx.z * (DM * DH);
  unsigned short* D = dst + (size_t)blockIdx.z * (DM * DH);
  int r0 = blockIdx.y * 64, c0 = blockIdx.x * 64;
  int t = threadIdx.x;
  int fc = (t & 15) * 4, rr = t >> 4;
#pragma unroll
  for (int i = 0; i < 4; ++i) {
    int r = rr + i * 16;
    float4 v = *(const float4*)&S[(size_t)(r0 + r) * 1024 + c0 + fc];
    tile[r][fc + 0] = v.x; tile[r][fc + 1] = v.y;
    tile[r][fc + 2] = v.z; tile[r][fc + 3] = v.w;
  }
  __syncthreads();
  int c = t >> 2;
  int rs = (t & 3) * 16;
#pragma unroll
  for (int j = 0; j < 2; ++j) {
    int rb = rs + j * 8;
    ushort8v o;
#pragma unroll
    for (int k = 0; k < 8; ++k) o[k] = f2bf(tile[rb + k][c]);
    *(ushort8v*)&D[(size_t)(c0 + c) * 1024 + r0 + rb] = o;
  }
}

// ---------------- gating: logits, softmax, top-2, renorm (no atomics) ----------------
__global__ __launch_bounds__(256) void k_route(const float* __restrict__ x,
                                               const float* __restrict__ gw,
                                               int* __restrict__ tok_e,
                                               float* __restrict__ tok_w) {
  int wave = threadIdx.x >> 6, lane = threadIdx.x & 63;
  int t = blockIdx.x * 4 + wave;
  const float* xt = x + (size_t)t * DM;
  float acc[NE];
#pragma unroll
  for (int e = 0; e < NE; ++e) acc[e] = 0.f;
  for (int i = lane; i < DM; i += 64) {
    float xi = xt[i];
#pragma unroll
    for (int e = 0; e < NE; ++e) acc[e] += xi * gw[e * DM + i];
  }
#pragma unroll
  for (int e = 0; e < NE; ++e) {
#pragma unroll
    for (int off = 32; off; off >>= 1) acc[e] += __shfl_xor(acc[e], off, 64);
  }
  if (lane == 0) {
    float m = acc[0];
#pragma unroll
    for (int e = 1; e < NE; ++e) m = fmaxf(m, acc[e]);
    float p[NE], s = 0.f;
#pragma unroll
    for (int e = 0; e < NE; ++e) { p[e] = __expf(acc[e] - m); s += p[e]; }
#pragma unroll
    for (int e = 0; e < NE; ++e) p[e] /= s;
    int i0 = 0;
#pragma unroll
    for (int e = 1; e < NE; ++e) if (p[e] > p[i0]) i0 = e;
    int i1 = (i0 == 0) ? 1 : 0;
#pragma unroll
    for (int e = 0; e < NE; ++e) if (e != i0 && p[e] > p[i1]) i1 = e;
    float w0 = p[i0], w1 = p[i1];
    float dnm = w0 + w1 + 1e-20f;
    w0 /= dnm; w1 /= dnm;
    tok_e[t * 2 + 0] = i0; tok_e[t * 2 + 1] = i1;
    tok_w[t * 2 + 0] = w0; tok_w[t * 2 + 1] = w1;
  }
}

// --------- slot assignment: single block, ballot-based stable counting sort ---------
// experts padded to 256 rows (GEMM tile = 256)
__global__ __launch_bounds__(1024) void k_slots(const int* __restrict__ tok_e,
                                                const float* __restrict__ tok_w,
                                                int* __restrict__ rows,
                                                float* __restrict__ rw,
                                                int* __restrict__ slot_of,
                                                int* __restrict__ po_g) {
  __shared__ unsigned short rank_s[NASSIGN];
  __shared__ int chunkcnt[128][NE];
  __shared__ int po_s[NE + 1];
  __shared__ int counts_s[NE];
  int tid = threadIdx.x, lane = tid & 63, wave = tid >> 6;
  unsigned long long below = (lane == 0) ? 0ull : ((~0ull) >> (64 - lane));
#pragma unroll
  for (int j = 0; j < 8; ++j) {
    int c = wave * 8 + j;
    int a = c * 64 + lane;
    int ei = tok_e[a];
    int myrank = 0, mycnt = 0;
#pragma unroll
    for (int e = 0; e < NE; ++e) {
      unsigned long long m = __ballot(ei == e);
      if (e == ei) myrank = __popcll(m & below);
      if (lane == e) mycnt = __popcll(m);
    }
    rank_s[a] = (unsigned short)myrank;
    if (lane < NE) chunkcnt[c][lane] = mycnt;
  }
  __syncthreads();
  if (tid < NE) {
    int run = 0;
    for (int c = 0; c < 128; ++c) {
      int v = chunkcnt[c][tid];
      chunkcnt[c][tid] = run;
      run += v;
    }
    counts_s[tid] = run;
  }
  __syncthreads();
  if (tid == 0) {
    int s = 0;
    po_s[0] = 0;
    for (int e = 0; e < NE; ++e) {
      s += ((counts_s[e] + 255) >> 8) << 8;   // pad to 256
      po_s[e + 1] = s;
    }
  }
  __syncthreads();
  if (tid < NE + 1) po_g[tid] = po_s[tid];
  int po8 = po_s[NE];
#pragma unroll
  for (int j = 0; j < 8; ++j) {
    int a = tid + j * 1024;
    int e = tok_e[a];
    int c = a >> 6;
    int slot = po_s[e] + chunkcnt[c][e] + (int)rank_s[a];
    rows[slot] = a >> 1;
    rw[slot] = tok_w[a];
    slot_of[a] = slot;
  }
  // shared-expert segment: slots [po8, po8+NTOK), identity rows, weight 1
  for (int s = tid; s < NTOK; s += 1024) {
    rows[po8 + s] = s;
    rw[po8 + s] = 1.f;
  }
  // pad slots inside expert segments
  for (int s = tid; s < MAXSLOT_E; s += 1024) {
    if (s >= po8) break;
    int e = 0;
#pragma unroll
    for (int i = 1; i < NE; ++i)
      if (s >= po_s[i]) e = i;
    if (s >= po_s[e] + counts_s[e]) { rows[s] = 0; rw[s] = 0.f; }
  }
}

// ---- grouped GEMM (shared = expert 8): 256x256 tile, BK=64, 8 waves, 8-phase ----
// UP: A gathered via rows[], silu -> bf16 H.  !UP: A direct (slot space);
//     e<8 -> bf16 YE * rw; e==8 -> fp32 out (token = slot - po8).
template <bool UP>
__global__ __launch_bounds__(512, 2) void k_gemm(const unsigned short* __restrict__ A,
                                                 const unsigned short* __restrict__ Be,
                                                 const unsigned short* __restrict__ Bsh,
                                                 const float* __restrict__ be,
                                                 const float* __restrict__ bsh,
                                                 const int* __restrict__ rows,
                                                 const float* __restrict__ rw,
                                                 const int* __restrict__ po,
                                                 unsigned short* __restrict__ OutB,
                                                 float* __restrict__ OutF) {
  // [buf][half][row 0..127][kslot(16B) 0..7 swizzled], row stride 128B
  __shared__ unsigned short LA[2][2][128 * 64];
  __shared__ unsigned short LB[2][2][128 * 64];
  int id = blockIdx.x;
  int rt = id % NRT2, ct = id / NRT2;
  int row0 = rt * 256;
  int po8 = po[NE];
  if (row0 >= po8 + NTOK) return;
  int e = NE;  // shared
  if (row0 < po8) {
    e = 0;
#pragma unroll
    for (int i = 1; i < NE; ++i)
      if (row0 >= po[i]) e = i;
  }
  const unsigned short* Bm = (e < NE) ? Be + (size_t)e * (DM * DH) : Bsh;
  const float* bia = (e < NE) ? be + (size_t)e * (UP ? DH : DM) : bsh;

  int tid = threadIdx.x, lane = tid & 63, w = tid >> 6;
  int wr = w >> 2, wc = w & 3, l15 = lane & 15;
  int s0 = (lane >> 4) ^ (lane & 7);  // kk=0 swizzled slot

  // ---- staging mapping: 1 load/thread/call covers one 64-row quadrant.
  // dest elem = (q*64 + (tid>>3))*64 + (tid&7)*8  ->  uniform + lane*16B  (required!)
  int st_r = tid >> 3;       // 0..63
  int st_s = tid & 7;
  int grA[2][2];
  if (UP) {
#pragma unroll
    for (int h = 0; h < 2; ++h)
#pragma unroll
      for (int q = 0; q < 2; ++q)
        grA[h][q] = rows[row0 + h * 128 + q * 64 + st_r];
  }

  f32x4 acc[8][4] = {};
  short8 a[4][2], b[4][2];

  auto STG_A = [&](int buf, int h, int q, int kt) {
    int lr = q * 64 + st_r;
    int gk = st_s ^ (lr & 7);
    int grow = UP ? grA[h][q] : (row0 + h * 128 + lr);
    async_ld16(A + (size_t)grow * 1024 + kt * 64 + gk * 8,
               &LA[buf][h][lr * 64 + st_s * 8]);
  };
  auto STG_B = [&](int buf, int h, int q, int kt) {
    int lr = q * 64 + st_r;
    int gk = st_s ^ (lr & 7);
    int gcol = ct * 256 + h * 128 + lr;
    async_ld16(Bm + (size_t)gcol * 1024 + kt * 64 + gk * 8,
               &LB[buf][h][lr * 64 + st_s * 8]);
  };

  const unsigned short* Ab_[2] = {&LA[0][wr][0], &LA[1][wr][0]};
  const unsigned short* Bb_[2] = {&LB[0][wc >> 1][0], &LB[1][wc >> 1][0]};
  int brow0 = (wc & 1) * 64 + l15;
  int sl[2] = {s0 * 8, (s0 ^ 4) * 8};

  auto RD_A = [&](int buf, int mq) {
#pragma unroll
    for (int m4 = 0; m4 < 4; ++m4)
#pragma unroll
      for (int kk = 0; kk < 2; ++kk)
        a[m4][kk] = *(const short8*)(Ab_[buf] + (mq * 64 + m4 * 16 + l15) * 64 + sl[kk]);
  };
  auto RD_B = [&](int buf, int np) {
#pragma unroll
    for (int n2 = 0; n2 < 2; ++n2)
#pragma unroll
      for (int kk = 0; kk < 2; ++kk)
        b[np * 2 + n2][kk] =
            *(const short8*)(Bb_[buf] + (brow0 + (np * 2 + n2) * 16) * 64 + sl[kk]);
  };
  auto MFMAQ = [&](int mq, int np) {
    __builtin_amdgcn_s_setprio(1);
#pragma unroll
    for (int m4 = 0; m4 < 4; ++m4)
#pragma unroll
      for (int n2 = 0; n2 < 2; ++n2)
#pragma unroll
        for (int kk = 0; kk < 2; ++kk)
          acc[mq * 4 + m4][np * 2 + n2] = __builtin_amdgcn_mfma_f32_16x16x32_bf16(
              a[m4][kk], b[np * 2 + n2][kk], acc[mq * 4 + m4][np * 2 + n2], 0, 0, 0);
    __builtin_amdgcn_s_setprio(0);
    __builtin_amdgcn_sched_barrier(0);
  };

  // ---- prologue: tile0 -> buf0 (8 loads), tile1 -> buf1 (8 loads)
  STG_A(0, 0, 0, 0); STG_A(0, 1, 0, 0); STG_A(0, 0, 1, 0); STG_A(0, 1, 1, 0);
  STG_B(0, 0, 0, 0); STG_B(0, 0, 1, 0); STG_B(0, 1, 0, 0); STG_B(0, 1, 1, 0);
  STG_A(1, 0, 0, 1); STG_A(1, 1, 0, 1); STG_A(1, 0, 1, 1); STG_A(1, 1, 1, 1);
  STG_B(1, 0, 0, 1); STG_B(1, 0, 1, 1); STG_B(1, 1, 0, 1); STG_B(1, 1, 1, 1);
  VMCNT(8);  // tile0 landed; tile1 in flight
  BARR();

  // ---- 8 iterations x 8 phases (2 K-tiles/iter); two barriers per phase.
  // Region lifetimes (reads drained via LGKM0 before the trailing barrier):
  //   A-q0 after ph1, B(all) after ph2, A-q1 after ph3  (mirror ph5..ph7).
  // Staging calendar: ph2: A-q0 x2 | ph3: B-h0 x2 | ph4: A-q1 x2 + B-h1 x2 +VMCNT(8).
  for (int it = 0; it < 8; ++it) {
    int tn = (2 * it + 2) & 15, un = (2 * it + 3) & 15;
    // tile 2it (buf0): quadrants (0,0)(0,1)(1,1)(1,0)
    RD_A(0, 0); RD_B(0, 0);
    BARR(); LGKM0(); MFMAQ(0, 0); BARR();                               // ph1
    RD_B(0, 1); STG_A(0, 0, 0, tn); STG_A(0, 1, 0, tn);
    BARR(); LGKM0(); MFMAQ(0, 1); BARR();                               // ph2
    RD_A(0, 1); STG_B(0, 0, 0, tn); STG_B(0, 0, 1, tn);
    BARR(); LGKM0(); MFMAQ(1, 1); BARR();                               // ph3
    STG_A(0, 0, 1, tn); STG_A(0, 1, 1, tn);
    STG_B(0, 1, 0, tn); STG_B(0, 1, 1, tn); VMCNT(8);
    BARR(); MFMAQ(1, 0); BARR();                                        // ph4
    // tile 2it+1 (buf1): mirror
    RD_A(1, 0); RD_B(1, 0);
    BARR(); LGKM0(); MFMAQ(0, 0); BARR();                               // ph5
    RD_B(1, 1); STG_A(1, 0, 0, un); STG_A(1, 1, 0, un);
    BARR(); LGKM0(); MFMAQ(0, 1); BARR();                               // ph6
    RD_A(1, 1); STG_B(1, 0, 0, un); STG_B(1, 0, 1, un);
    BARR(); LGKM0(); MFMAQ(1, 1); BARR();                               // ph7
    STG_A(1, 0, 1, un); STG_A(1, 1, 1, un);
    STG_B(1, 1, 0, un); STG_B(1, 1, 1, un); VMCNT(8);
    BARR(); MFMAQ(1, 0); BARR();                                        // ph8
  }
  VMCNT(0);  // drain wrapped dummy stages before epilogue

  // ---- epilogue
  int gcol0 = ct * 256 + wc * 64;
#pragma unroll
  for (int m = 0; m < 8; ++m) {
    int rbase = row0 + wr * 128 + m * 16 + ((lane >> 4) << 2);
#pragma unroll
    for (int j = 0; j < 4; ++j) {
      int grow = rbase + j;
#pragma unroll
      for (int n = 0; n < 4; ++n) {
        int gc = gcol0 + n * 16 + l15;
        float v = acc[m][n][j] + bia[gc];
        if (UP) {
          v = v / (1.f + __expf(-v));  // silu
          OutB[(size_t)grow * DH + gc] = f2bf(v);
        } else if (e < NE) {
          OutB[(size_t)grow * DM + gc] = f2bf(v * rw[grow]);
        } else {
          OutF[(size_t)(grow - po8) * DM + gc] = v;  // shared -> out fp32
        }
      }
    }
  }
}

// ---------------- final combine: out[t] += YE[s0] + YE[s1] ----------------
__global__ __launch_bounds__(256) void k_combine(float* __restrict__ out,
                                                 const unsigned short* __restrict__ YE,
                                                 const int* __restrict__ slot_of) {
  int t = blockIdx.x;
  int s0 = slot_of[t * 2 + 0], s1 = slot_of[t * 2 + 1];
  int c = threadIdx.x * 4;
  float* op = out + (size_t)t * DM + c;
  float4 o = *(float4*)op;
  ushort4 a = *(const ushort4*)(YE + (size_t)s0 * DM + c);
  ushort4 b = *(const ushort4*)(YE + (size_t)s1 * DM + c);
  o.x += bf2f(a.x) + bf2f(b.x);
  o.y += bf2f(a.y) + bf2f(b.y);
  o.z += bf2f(a.z) + bf2f(b.z);
  o.w += bf2f(a.w) + bf2f(b.w);
  *(float4*)op = o;
}

extern "C" void kernel_launch(void* const* d_in, const int* in_sizes, int n_in,
                              void* d_out, int out_size, void* d_ws, size_t ws_size,
                              hipStream_t stream) {
  const float* x        = (const float*)d_in[0];
  const float* gate_w   = (const float*)d_in[1];
  const float* up_w     = (const float*)d_in[2];
  const float* up_b     = (const float*)d_in[3];
  const float* down_w   = (const float*)d_in[4];
  const float* down_b   = (const float*)d_in[5];
  const float* sh_up_w  = (const float*)d_in[6];
  const float* sh_up_b  = (const float*)d_in[7];
  const float* sh_dn_w  = (const float*)d_in[8];
  const float* sh_dn_b  = (const float*)d_in[9];
  float* out = (float*)d_out;

  // Manual workspace layout (YE aliases xb+upT: both fully rewritten each call
  // before their consumers, and dead by the time YE is produced).
  char* ws = (char*)d_ws;
  const size_t MB = 1024 * 1024;
  unsigned short* xb   = (unsigned short*)(ws + 0);          // 8 MB
  unsigned short* upT  = (unsigned short*)(ws + 8 * MB);     // 16 MB
  unsigned short* dnT  = (unsigned short*)(ws + 24 * MB);    // 16 MB
  unsigned short* shuT = (unsigned short*)(ws + 40 * MB);    // 2 MB
  unsigned short* shdT = (unsigned short*)(ws + 42 * MB);    // 2 MB
  unsigned short* H    = (unsigned short*)(ws + 44 * MB);    // 28 MB (14336*1024*2)
  char* tail = ws + 44 * MB + (size_t)MAXSLOT_ALL * DH * 2;
  int*   tok_e   = (int*)tail;                tail += NASSIGN * 4;
  float* tok_w   = (float*)tail;              tail += NASSIGN * 4;
  int*   slot_of = (int*)tail;                tail += NASSIGN * 4;
  int*   rows    = (int*)tail;                tail += MAXSLOT_ALL * 4;
  float* rw      = (float*)tail;              tail += MAXSLOT_ALL * 4;
  int*   po      = (int*)tail;                tail += 64;
  unsigned short* YE = (unsigned short*)(ws + 0);            // alias, 20 MB < 24 MB

  // 1) dtype conversions / weight transposes
  k_cvt<<<(NTOK * DM) / 1024, 256, 0, stream>>>(x, xb, NTOK * DM);
  k_tcvt<<<dim3(16, 16, NE), 256, 0, stream>>>(up_w, upT);
  k_tcvt<<<dim3(16, 16, NE), 256, 0, stream>>>(down_w, dnT);
  k_tcvt<<<dim3(16, 16, 1), 256, 0, stream>>>(sh_up_w, shuT);
  k_tcvt<<<dim3(16, 16, 1), 256, 0, stream>>>(sh_dn_w, shdT);

  // 2) routing (no atomics)
  k_route<<<NTOK / 4, 256, 0, stream>>>(x, gate_w, tok_e, tok_w);
  k_slots<<<1, 1024, 0, stream>>>(tok_e, tok_w, rows, rw, slot_of, po);

  // 3) grouped GEMMs (experts 0..7 + shared as 8), 256x256 8-phase
  k_gemm<true><<<GRID_G, 512, 0, stream>>>(
      xb, upT, shuT, up_b, sh_up_b, rows, rw, po, H, nullptr);
  k_gemm<false><<<GRID_G, 512, 0, stream>>>(
      H, dnT, shdT, down_b, sh_dn_b, rows, rw, po, YE, out);

  // 4) combine
  k_combine<<<NTOK, 256, 0, stream>>>(out, YE, slot_of);
}

// Round 9
// 156.778 us; speedup vs baseline: 1.0468x; 1.0468x over previous
//
#include <hip/hip_runtime.h>
#include <hip/hip_bf16.h>
#include <cstdint>
#include <cstddef>

// MoE FFN: x[2,2048,1024] fp32, 8 experts top-2 + 1 shared expert.
// R1: no-atomic routing (ballot-based slot sort).
// R2: shared expert fused as expert #8 into grouped GEMMs.
// R3: LDS swizzle (bank conflicts -> 0).
// R6/R8: 256x256 8-wave 8-phase GEMM, quadrant staging, counted vmcnt(8).
// R9: XCD-chunked swizzle ON the 8-phase kernel (T1+T3/T4 complement: 4-phase
//     ledger cover matches L2 latency only if loads actually hit L2);
//     all 4 weight transposes fused into one dispatch.

#define NTOK 4096
#define DM 1024
#define DH 1024
#define NE 8
#define MAXSLOT_E 10240           // 8192 assignments + 8*256 padding (worst case)
#define MAXSLOT_ALL (MAXSLOT_E + NTOK)  // + shared segment (4096) = 14336
#define NASSIGN (NTOK * 2)
#define NRT2 (MAXSLOT_ALL / 256)  // 56 row tiles
#define GRID_G (NRT2 * 4)         // 224 blocks (4 col tiles), 224 % 8 == 0

typedef __attribute__((ext_vector_type(8))) short short8;
typedef __attribute__((ext_vector_type(8))) unsigned short ushort8v;
typedef __attribute__((ext_vector_type(4))) float f32x4;

__device__ __forceinline__ unsigned short f2bf(float f) {
  uint32_t u = __float_as_uint(f);
  return (unsigned short)((u + 0x7FFFu + ((u >> 16) & 1u)) >> 16);  // RNE
}
__device__ __forceinline__ float bf2f(unsigned short h) {
  return __uint_as_float(((uint32_t)h) << 16);
}

__device__ __forceinline__ void async_ld16(const void* g, void* l) {
  __builtin_amdgcn_global_load_lds(
      (const __attribute__((address_space(1))) void*)g,
      (__attribute__((address_space(3))) void*)l, 16, 0, 0);
}

__device__ __forceinline__ void BARR() {
  asm volatile("" ::: "memory");
  __builtin_amdgcn_s_barrier();
  asm volatile("" ::: "memory");
}
__device__ __forceinline__ void LGKM0() {
  asm volatile("s_waitcnt lgkmcnt(0)" ::: "memory");
  __builtin_amdgcn_sched_barrier(0);
}
#define VMCNT(n) asm volatile("s_waitcnt vmcnt(" #n ")" ::: "memory")

// ---------------- fp32 -> bf16 convert (no transpose) ----------------
__global__ __launch_bounds__(256) void k_cvt(const float* __restrict__ s,
                                             unsigned short* __restrict__ d, int n) {
  int i = (blockIdx.x * 256 + threadIdx.x) * 4;
  if (i >= n) return;
  float4 v = *(const float4*)(s + i);
  ushort4 o;
  o.x = f2bf(v.x); o.y = f2bf(v.y); o.z = f2bf(v.z); o.w = f2bf(v.w);
  *(ushort4*)(d + i) = o;
}

// --- fp32 [1024][1024] -> bf16 transposed, ALL weight matrices in one dispatch ---
// z: 0..7 up_w expert z | 8..15 down_w expert z-8 | 16 sh_up | 17 sh_down
__global__ __launch_bounds__(256) void k_tcvt_all(const float* __restrict__ up_w,
                                                  const float* __restrict__ down_w,
                                                  const float* __restrict__ sh_up,
                                                  const float* __restrict__ sh_dn,
                                                  unsigned short* __restrict__ upT,
                                                  unsigned short* __restrict__ dnT,
                                                  unsigned short* __restrict__ shuT,
                                                  unsigned short* __restrict__ shdT) {
  __shared__ float tile[64][65];
  int z = blockIdx.z;
  const float* S;
  unsigned short* D;
  if (z < 8)       { S = up_w   + (size_t)z * (DM * DH);       D = upT + (size_t)z * (DM * DH); }
  else if (z < 16) { S = down_w + (size_t)(z - 8) * (DM * DH); D = dnT + (size_t)(z - 8) * (DM * DH); }
  else if (z == 16){ S = sh_up;  D = shuT; }
  else             { S = sh_dn;  D = shdT; }
  int r0 = blockIdx.y * 64, c0 = blockIdx.x * 64;
  int t = threadIdx.x;
  int fc = (t & 15) * 4, rr = t >> 4;
#pragma unroll
  for (int i = 0; i < 4; ++i) {
    int r = rr + i * 16;
    float4 v = *(const float4*)&S[(size_t)(r0 + r) * 1024 + c0 + fc];
    tile[r][fc + 0] = v.x; tile[r][fc + 1] = v.y;
    tile[r][fc + 2] = v.z; tile[r][fc + 3] = v.w;
  }
  __syncthreads();
  int c = t >> 2;
  int rs = (t & 3) * 16;
#pragma unroll
  for (int j = 0; j < 2; ++j) {
    int rb = rs + j * 8;
    ushort8v o;
#pragma unroll
    for (int k = 0; k < 8; ++k) o[k] = f2bf(tile[rb + k][c]);
    *(ushort8v*)&D[(size_t)(c0 + c) * 1024 + r0 + rb] = o;
  }
}

// ---------------- gating: logits, softmax, top-2, renorm (no atomics) ----------------
__global__ __launch_bounds__(256) void k_route(const float* __restrict__ x,
                                               const float* __restrict__ gw,
                                               int* __restrict__ tok_e,
                                               float* __restrict__ tok_w) {
  int wave = threadIdx.x >> 6, lane = threadIdx.x & 63;
  int t = blockIdx.x * 4 + wave;
  const float* xt = x + (size_t)t * DM;
  float acc[NE];
#pragma unroll
  for (int e = 0; e < NE; ++e) acc[e] = 0.f;
  for (int i = lane; i < DM; i += 64) {
    float xi = xt[i];
#pragma unroll
    for (int e = 0; e < NE; ++e) acc[e] += xi * gw[e * DM + i];
  }
#pragma unroll
  for (int e = 0; e < NE; ++e) {
#pragma unroll
    for (int off = 32; off; off >>= 1) acc[e] += __shfl_xor(acc[e], off, 64);
  }
  if (lane == 0) {
    float m = acc[0];
#pragma unroll
    for (int e = 1; e < NE; ++e) m = fmaxf(m, acc[e]);
    float p[NE], s = 0.f;
#pragma unroll
    for (int e = 0; e < NE; ++e) { p[e] = __expf(acc[e] - m); s += p[e]; }
#pragma unroll
    for (int e = 0; e < NE; ++e) p[e] /= s;
    int i0 = 0;
#pragma unroll
    for (int e = 1; e < NE; ++e) if (p[e] > p[i0]) i0 = e;
    int i1 = (i0 == 0) ? 1 : 0;
#pragma unroll
    for (int e = 0; e < NE; ++e) if (e != i0 && p[e] > p[i1]) i1 = e;
    float w0 = p[i0], w1 = p[i1];
    float dnm = w0 + w1 + 1e-20f;
    w0 /= dnm; w1 /= dnm;
    tok_e[t * 2 + 0] = i0; tok_e[t * 2 + 1] = i1;
    tok_w[t * 2 + 0] = w0; tok_w[t * 2 + 1] = w1;
  }
}

// --------- slot assignment: single block, ballot-based stable counting sort ---------
// experts padded to 256 rows (GEMM tile = 256)
__global__ __launch_bounds__(1024) void k_slots(const int* __restrict__ tok_e,
                                                const float* __restrict__ tok_w,
                                                int* __restrict__ rows,
                                                float* __restrict__ rw,
                                                int* __restrict__ slot_of,
                                                int* __restrict__ po_g) {
  __shared__ unsigned short rank_s[NASSIGN];
  __shared__ int chunkcnt[128][NE];
  __shared__ int po_s[NE + 1];
  __shared__ int counts_s[NE];
  int tid = threadIdx.x, lane = tid & 63, wave = tid >> 6;
  unsigned long long below = (lane == 0) ? 0ull : ((~0ull) >> (64 - lane));
#pragma unroll
  for (int j = 0; j < 8; ++j) {
    int c = wave * 8 + j;
    int a = c * 64 + lane;
    int ei = tok_e[a];
    int myrank = 0, mycnt = 0;
#pragma unroll
    for (int e = 0; e < NE; ++e) {
      unsigned long long m = __ballot(ei == e);
      if (e == ei) myrank = __popcll(m & below);
      if (lane == e) mycnt = __popcll(m);
    }
    rank_s[a] = (unsigned short)myrank;
    if (lane < NE) chunkcnt[c][lane] = mycnt;
  }
  __syncthreads();
  if (tid < NE) {
    int run = 0;
    for (int c = 0; c < 128; ++c) {
      int v = chunkcnt[c][tid];
      chunkcnt[c][tid] = run;
      run += v;
    }
    counts_s[tid] = run;
  }
  __syncthreads();
  if (tid == 0) {
    int s = 0;
    po_s[0] = 0;
    for (int e = 0; e < NE; ++e) {
      s += ((counts_s[e] + 255) >> 8) << 8;   // pad to 256
      po_s[e + 1] = s;
    }
  }
  __syncthreads();
  if (tid < NE + 1) po_g[tid] = po_s[tid];
  int po8 = po_s[NE];
#pragma unroll
  for (int j = 0; j < 8; ++j) {
    int a = tid + j * 1024;
    int e = tok_e[a];
    int c = a >> 6;
    int slot = po_s[e] + chunkcnt[c][e] + (int)rank_s[a];
    rows[slot] = a >> 1;
    rw[slot] = tok_w[a];
    slot_of[a] = slot;
  }
  // shared-expert segment: slots [po8, po8+NTOK), identity rows, weight 1
  for (int s = tid; s < NTOK; s += 1024) {
    rows[po8 + s] = s;
    rw[po8 + s] = 1.f;
  }
  // pad slots inside expert segments
  for (int s = tid; s < MAXSLOT_E; s += 1024) {
    if (s >= po8) break;
    int e = 0;
#pragma unroll
    for (int i = 1; i < NE; ++i)
      if (s >= po_s[i]) e = i;
    if (s >= po_s[e] + counts_s[e]) { rows[s] = 0; rw[s] = 0.f; }
  }
}

// ---- grouped GEMM (shared = expert 8): 256x256 tile, BK=64, 8 waves, 8-phase ----
// XCD-chunked swizzle: XCD k owns rt in [7k, 7k+7) x all 4 ct -> B k-slice +
// A tiles L2-resident; ledger cover (~4 phases) then hides L2 latency.
// UP: A gathered via rows[], silu -> bf16 H.  !UP: A direct (slot space);
//     e<8 -> bf16 YE * rw; e==8 -> fp32 out (token = slot - po8).
template <bool UP>
__global__ __launch_bounds__(512, 2) void k_gemm(const unsigned short* __restrict__ A,
                                                 const unsigned short* __restrict__ Be,
                                                 const unsigned short* __restrict__ Bsh,
                                                 const float* __restrict__ be,
                                                 const float* __restrict__ bsh,
                                                 const int* __restrict__ rows,
                                                 const float* __restrict__ rw,
                                                 const int* __restrict__ po,
                                                 unsigned short* __restrict__ OutB,
                                                 float* __restrict__ OutF) {
  // [buf][half][row 0..127][kslot(16B) 0..7 swizzled], row stride 128B
  __shared__ unsigned short LA[2][2][128 * 64];
  __shared__ unsigned short LB[2][2][128 * 64];
  // bijective XCD-chunked swizzle (GRID_G % 8 == 0), rt-major within XCD
  int orig = blockIdx.x;
  int wgid = (orig & 7) * (GRID_G / 8) + (orig >> 3);
  int rt = wgid >> 2, ct = wgid & 3;
  int row0 = rt * 256;
  int po8 = po[NE];
  if (row0 >= po8 + NTOK) return;
  int e = NE;  // shared
  if (row0 < po8) {
    e = 0;
#pragma unroll
    for (int i = 1; i < NE; ++i)
      if (row0 >= po[i]) e = i;
  }
  const unsigned short* Bm = (e < NE) ? Be + (size_t)e * (DM * DH) : Bsh;
  const float* bia = (e < NE) ? be + (size_t)e * (UP ? DH : DM) : bsh;

  int tid = threadIdx.x, lane = tid & 63, w = tid >> 6;
  int wr = w >> 2, wc = w & 3, l15 = lane & 15;
  int s0 = (lane >> 4) ^ (lane & 7);  // kk=0 swizzled slot

  // ---- staging mapping: 1 load/thread/call covers one 64-row quadrant.
  // dest elem = (q*64 + (tid>>3))*64 + (tid&7)*8  ->  uniform + lane*16B  (required!)
  int st_r = tid >> 3;       // 0..63
  int st_s = tid & 7;
  int grA[2][2];
  if (UP) {
#pragma unroll
    for (int h = 0; h < 2; ++h)
#pragma unroll
      for (int q = 0; q < 2; ++q)
        grA[h][q] = rows[row0 + h * 128 + q * 64 + st_r];
  }

  f32x4 acc[8][4] = {};
  short8 a[4][2], b[4][2];

  auto STG_A = [&](int buf, int h, int q, int kt) {
    int lr = q * 64 + st_r;
    int gk = st_s ^ (lr & 7);
    int grow = UP ? grA[h][q] : (row0 + h * 128 + lr);
    async_ld16(A + (size_t)grow * 1024 + kt * 64 + gk * 8,
               &LA[buf][h][lr * 64 + st_s * 8]);
  };
  auto STG_B = [&](int buf, int h, int q, int kt) {
    int lr = q * 64 + st_r;
    int gk = st_s ^ (lr & 7);
    int gcol = ct * 256 + h * 128 + lr;
    async_ld16(Bm + (size_t)gcol * 1024 + kt * 64 + gk * 8,
               &LB[buf][h][lr * 64 + st_s * 8]);
  };

  const unsigned short* Ab_[2] = {&LA[0][wr][0], &LA[1][wr][0]};
  const unsigned short* Bb_[2] = {&LB[0][wc >> 1][0], &LB[1][wc >> 1][0]};
  int brow0 = (wc & 1) * 64 + l15;
  int sl[2] = {s0 * 8, (s0 ^ 4) * 8};

  auto RD_A = [&](int buf, int mq) {
#pragma unroll
    for (int m4 = 0; m4 < 4; ++m4)
#pragma unroll
      for (int kk = 0; kk < 2; ++kk)
        a[m4][kk] = *(const short8*)(Ab_[buf] + (mq * 64 + m4 * 16 + l15) * 64 + sl[kk]);
  };
  auto RD_B = [&](int buf, int np) {
#pragma unroll
    for (int n2 = 0; n2 < 2; ++n2)
#pragma unroll
      for (int kk = 0; kk < 2; ++kk)
        b[np * 2 + n2][kk] =
            *(const short8*)(Bb_[buf] + (brow0 + (np * 2 + n2) * 16) * 64 + sl[kk]);
  };
  auto MFMAQ = [&](int mq, int np) {
    __builtin_amdgcn_s_setprio(1);
#pragma unroll
    for (int m4 = 0; m4 < 4; ++m4)
#pragma unroll
      for (int n2 = 0; n2 < 2; ++n2)
#pragma unroll
        for (int kk = 0; kk < 2; ++kk)
          acc[mq * 4 + m4][np * 2 + n2] = __builtin_amdgcn_mfma_f32_16x16x32_bf16(
              a[m4][kk], b[np * 2 + n2][kk], acc[mq * 4 + m4][np * 2 + n2], 0, 0, 0);
    __builtin_amdgcn_s_setprio(0);
    __builtin_amdgcn_sched_barrier(0);
  };

  // ---- prologue: tile0 -> buf0 (8 loads), tile1 -> buf1 (8 loads)
  STG_A(0, 0, 0, 0); STG_A(0, 1, 0, 0); STG_A(0, 0, 1, 0); STG_A(0, 1, 1, 0);
  STG_B(0, 0, 0, 0); STG_B(0, 0, 1, 0); STG_B(0, 1, 0, 0); STG_B(0, 1, 1, 0);
  STG_A(1, 0, 0, 1); STG_A(1, 1, 0, 1); STG_A(1, 0, 1, 1); STG_A(1, 1, 1, 1);
  STG_B(1, 0, 0, 1); STG_B(1, 0, 1, 1); STG_B(1, 1, 0, 1); STG_B(1, 1, 1, 1);
  VMCNT(8);  // tile0 landed; tile1 in flight
  BARR();

  // ---- 8 iterations x 8 phases (2 K-tiles/iter); two barriers per phase.
  // Region lifetimes (reads drained via LGKM0 before the trailing barrier):
  //   A-q0 after ph1, B(all) after ph2, A-q1 after ph3  (mirror ph5..ph7).
  // Staging calendar: ph2: A-q0 x2 | ph3: B-h0 x2 | ph4: A-q1 x2 + B-h1 x2 +VMCNT(8).
  for (int it = 0; it < 8; ++it) {
    int tn = (2 * it + 2) & 15, un = (2 * it + 3) & 15;
    // tile 2it (buf0): quadrants (0,0)(0,1)(1,1)(1,0)
    RD_A(0, 0); RD_B(0, 0);
    BARR(); LGKM0(); MFMAQ(0, 0); BARR();                               // ph1
    RD_B(0, 1); STG_A(0, 0, 0, tn); STG_A(0, 1, 0, tn);
    BARR(); LGKM0(); MFMAQ(0, 1); BARR();                               // ph2
    RD_A(0, 1); STG_B(0, 0, 0, tn); STG_B(0, 0, 1, tn);
    BARR(); LGKM0(); MFMAQ(1, 1); BARR();                               // ph3
    STG_A(0, 0, 1, tn); STG_A(0, 1, 1, tn);
    STG_B(0, 1, 0, tn); STG_B(0, 1, 1, tn); VMCNT(8);
    BARR(); MFMAQ(1, 0); BARR();                                        // ph4
    // tile 2it+1 (buf1): mirror
    RD_A(1, 0); RD_B(1, 0);
    BARR(); LGKM0(); MFMAQ(0, 0); BARR();                               // ph5
    RD_B(1, 1); STG_A(1, 0, 0, un); STG_A(1, 1, 0, un);
    BARR(); LGKM0(); MFMAQ(0, 1); BARR();                               // ph6
    RD_A(1, 1); STG_B(1, 0, 0, un); STG_B(1, 0, 1, un);
    BARR(); LGKM0(); MFMAQ(1, 1); BARR();                               // ph7
    STG_A(1, 0, 1, un); STG_A(1, 1, 1, un);
    STG_B(1, 1, 0, un); STG_B(1, 1, 1, un); VMCNT(8);
    BARR(); MFMAQ(1, 0); BARR();                                        // ph8
  }
  VMCNT(0);  // drain wrapped dummy stages before epilogue

  // ---- epilogue
  int gcol0 = ct * 256 + wc * 64;
#pragma unroll
  for (int m = 0; m < 8; ++m) {
    int rbase = row0 + wr * 128 + m * 16 + ((lane >> 4) << 2);
#pragma unroll
    for (int j = 0; j < 4; ++j) {
      int grow = rbase + j;
#pragma unroll
      for (int n = 0; n < 4; ++n) {
        int gc = gcol0 + n * 16 + l15;
        float v = acc[m][n][j] + bia[gc];
        if (UP) {
          v = v / (1.f + __expf(-v));  // silu
          OutB[(size_t)grow * DH + gc] = f2bf(v);
        } else if (e < NE) {
          OutB[(size_t)grow * DM + gc] = f2bf(v * rw[grow]);
        } else {
          OutF[(size_t)(grow - po8) * DM + gc] = v;  // shared -> out fp32
        }
      }
    }
  }
}

// ---------------- final combine: out[t] += YE[s0] + YE[s1] ----------------
__global__ __launch_bounds__(256) void k_combine(float* __restrict__ out,
                                                 const unsigned short* __restrict__ YE,
                                                 const int* __restrict__ slot_of) {
  int t = blockIdx.x;
  int s0 = slot_of[t * 2 + 0], s1 = slot_of[t * 2 + 1];
  int c = threadIdx.x * 4;
  float* op = out + (size_t)t * DM + c;
  float4 o = *(float4*)op;
  ushort4 a = *(const ushort4*)(YE + (size_t)s0 * DM + c);
  ushort4 b = *(const ushort4*)(YE + (size_t)s1 * DM + c);
  o.x += bf2f(a.x) + bf2f(b.x);
  o.y += bf2f(a.y) + bf2f(b.y);
  o.z += bf2f(a.z) + bf2f(b.z);
  o.w += bf2f(a.w) + bf2f(b.w);
  *(float4*)op = o;
}

extern "C" void kernel_launch(void* const* d_in, const int* in_sizes, int n_in,
                              void* d_out, int out_size, void* d_ws, size_t ws_size,
                              hipStream_t stream) {
  const float* x        = (const float*)d_in[0];
  const float* gate_w   = (const float*)d_in[1];
  const float* up_w     = (const float*)d_in[2];
  const float* up_b     = (const float*)d_in[3];
  const float* down_w   = (const float*)d_in[4];
  const float* down_b   = (const float*)d_in[5];
  const float* sh_up_w  = (const float*)d_in[6];
  const float* sh_up_b  = (const float*)d_in[7];
  const float* sh_dn_w  = (const float*)d_in[8];
  const float* sh_dn_b  = (const float*)d_in[9];
  float* out = (float*)d_out;

  // Manual workspace layout (YE aliases xb+upT: both fully rewritten each call
  // before their consumers, and dead by the time YE is produced).
  char* ws = (char*)d_ws;
  const size_t MB = 1024 * 1024;
  unsigned short* xb   = (unsigned short*)(ws + 0);          // 8 MB
  unsigned short* upT  = (unsigned short*)(ws + 8 * MB);     // 16 MB
  unsigned short* dnT  = (unsigned short*)(ws + 24 * MB);    // 16 MB
  unsigned short* shuT = (unsigned short*)(ws + 40 * MB);    // 2 MB
  unsigned short* shdT = (unsigned short*)(ws + 42 * MB);    // 2 MB
  unsigned short* H    = (unsigned short*)(ws + 44 * MB);    // 28 MB (14336*1024*2)
  char* tail = ws + 44 * MB + (size_t)MAXSLOT_ALL * DH * 2;
  int*   tok_e   = (int*)tail;                tail += NASSIGN * 4;
  float* tok_w   = (float*)tail;              tail += NASSIGN * 4;
  int*   slot_of = (int*)tail;                tail += NASSIGN * 4;
  int*   rows    = (int*)tail;                tail += MAXSLOT_ALL * 4;
  float* rw      = (float*)tail;              tail += MAXSLOT_ALL * 4;
  int*   po      = (int*)tail;                tail += 64;
  unsigned short* YE = (unsigned short*)(ws + 0);            // alias, 20 MB < 24 MB

  // 1) dtype conversions / weight transposes (one fused dispatch for weights)
  k_cvt<<<(NTOK * DM) / 1024, 256, 0, stream>>>(x, xb, NTOK * DM);
  k_tcvt_all<<<dim3(16, 16, 18), 256, 0, stream>>>(up_w, down_w, sh_up_w, sh_dn_w,
                                                   upT, dnT, shuT, shdT);

  // 2) routing (no atomics)
  k_route<<<NTOK / 4, 256, 0, stream>>>(x, gate_w, tok_e, tok_w);
  k_slots<<<1, 1024, 0, stream>>>(tok_e, tok_w, rows, rw, slot_of, po);

  // 3) grouped GEMMs (experts 0..7 + shared as 8), 256x256 8-phase, XCD-swizzled
  k_gemm<true><<<GRID_G, 512, 0, stream>>>(
      xb, upT, shuT, up_b, sh_up_b, rows, rw, po, H, nullptr);
  k_gemm<false><<<GRID_G, 512, 0, stream>>>(
      H, dnT, shdT, down_b, sh_dn_b, rows, rw, po, YE, out);

  // 4) combine
  k_combine<<<NTOK, 256, 0, stream>>>(out, YE, slot_of);
}

// Round 10
// 153.230 us; speedup vs baseline: 1.0710x; 1.0232x over previous
//
#include <hip/hip_runtime.h>
#include <hip/hip_bf16.h>
#include <cstdint>
#include <cstddef>

// MoE FFN: x[2,2048,1024] fp32, 8 experts top-2 + 1 shared expert.
// R1: no-atomic routing.  R2: shared expert fused as expert #8.
// R3: LDS swizzle (conflicts 0).  R6/R8: 256x256 8-wave 8-phase, vmcnt ledger.
// R9: XCD-chunked swizzle (FETCH -> compulsory ~31MB).
// R10: register-fragment software pipeline: ds_reads for phase p+1 issue AFTER
//      MFMA(p) so the LDS pipe (the real bottleneck: 96 b128/phase ~ 1150cy/CU)
//      overlaps the MFMA pipe drain (621cy/CU). One barrier per phase.

#define NTOK 4096
#define DM 1024
#define DH 1024
#define NE 8
#define MAXSLOT_E 10240           // 8192 assignments + 8*256 padding (worst case)
#define MAXSLOT_ALL (MAXSLOT_E + NTOK)  // + shared segment (4096) = 14336
#define NASSIGN (NTOK * 2)
#define NRT2 (MAXSLOT_ALL / 256)  // 56 row tiles
#define GRID_G (NRT2 * 4)         // 224 blocks (4 col tiles), 224 % 8 == 0

typedef __attribute__((ext_vector_type(8))) short short8;
typedef __attribute__((ext_vector_type(8))) unsigned short ushort8v;
typedef __attribute__((ext_vector_type(4))) float f32x4;

__device__ __forceinline__ unsigned short f2bf(float f) {
  uint32_t u = __float_as_uint(f);
  return (unsigned short)((u + 0x7FFFu + ((u >> 16) & 1u)) >> 16);  // RNE
}
__device__ __forceinline__ float bf2f(unsigned short h) {
  return __uint_as_float(((uint32_t)h) << 16);
}

__device__ __forceinline__ void async_ld16(const void* g, void* l) {
  __builtin_amdgcn_global_load_lds(
      (const __attribute__((address_space(1))) void*)g,
      (__attribute__((address_space(3))) void*)l, 16, 0, 0);
}

__device__ __forceinline__ void BARR() {
  asm volatile("" ::: "memory");
  __builtin_amdgcn_s_barrier();
  asm volatile("" ::: "memory");
}
__device__ __forceinline__ void LGKM0() {
  asm volatile("s_waitcnt lgkmcnt(0)" ::: "memory");
  __builtin_amdgcn_sched_barrier(0);
}
#define VMCNT(n) asm volatile("s_waitcnt vmcnt(" #n ")" ::: "memory")

// ---------------- fp32 -> bf16 convert (no transpose) ----------------
__global__ __launch_bounds__(256) void k_cvt(const float* __restrict__ s,
                                             unsigned short* __restrict__ d, int n) {
  int i = (blockIdx.x * 256 + threadIdx.x) * 4;
  if (i >= n) return;
  float4 v = *(const float4*)(s + i);
  ushort4 o;
  o.x = f2bf(v.x); o.y = f2bf(v.y); o.z = f2bf(v.z); o.w = f2bf(v.w);
  *(ushort4*)(d + i) = o;
}

// --- fp32 [1024][1024] -> bf16 transposed, ALL weight matrices in one dispatch ---
__global__ __launch_bounds__(256) void k_tcvt_all(const float* __restrict__ up_w,
                                                  const float* __restrict__ down_w,
                                                  const float* __restrict__ sh_up,
                                                  const float* __restrict__ sh_dn,
                                                  unsigned short* __restrict__ upT,
                                                  unsigned short* __restrict__ dnT,
                                                  unsigned short* __restrict__ shuT,
                                                  unsigned short* __restrict__ shdT) {
  __shared__ float tile[64][65];
  int z = blockIdx.z;
  const float* S;
  unsigned short* D;
  if (z < 8)       { S = up_w   + (size_t)z * (DM * DH);       D = upT + (size_t)z * (DM * DH); }
  else if (z < 16) { S = down_w + (size_t)(z - 8) * (DM * DH); D = dnT + (size_t)(z - 8) * (DM * DH); }
  else if (z == 16){ S = sh_up;  D = shuT; }
  else             { S = sh_dn;  D = shdT; }
  int r0 = blockIdx.y * 64, c0 = blockIdx.x * 64;
  int t = threadIdx.x;
  int fc = (t & 15) * 4, rr = t >> 4;
#pragma unroll
  for (int i = 0; i < 4; ++i) {
    int r = rr + i * 16;
    float4 v = *(const float4*)&S[(size_t)(r0 + r) * 1024 + c0 + fc];
    tile[r][fc + 0] = v.x; tile[r][fc + 1] = v.y;
    tile[r][fc + 2] = v.z; tile[r][fc + 3] = v.w;
  }
  __syncthreads();
  int c = t >> 2;
  int rs = (t & 3) * 16;
#pragma unroll
  for (int j = 0; j < 2; ++j) {
    int rb = rs + j * 8;
    ushort8v o;
#pragma unroll
    for (int k = 0; k < 8; ++k) o[k] = f2bf(tile[rb + k][c]);
    *(ushort8v*)&D[(size_t)(c0 + c) * 1024 + r0 + rb] = o;
  }
}

// ---------------- gating: logits, softmax, top-2, renorm (no atomics) ----------------
__global__ __launch_bounds__(256) void k_route(const float* __restrict__ x,
                                               const float* __restrict__ gw,
                                               int* __restrict__ tok_e,
                                               float* __restrict__ tok_w) {
  int wave = threadIdx.x >> 6, lane = threadIdx.x & 63;
  int t = blockIdx.x * 4 + wave;
  const float* xt = x + (size_t)t * DM;
  float acc[NE];
#pragma unroll
  for (int e = 0; e < NE; ++e) acc[e] = 0.f;
  for (int i = lane; i < DM; i += 64) {
    float xi = xt[i];
#pragma unroll
    for (int e = 0; e < NE; ++e) acc[e] += xi * gw[e * DM + i];
  }
#pragma unroll
  for (int e = 0; e < NE; ++e) {
#pragma unroll
    for (int off = 32; off; off >>= 1) acc[e] += __shfl_xor(acc[e], off, 64);
  }
  if (lane == 0) {
    float m = acc[0];
#pragma unroll
    for (int e = 1; e < NE; ++e) m = fmaxf(m, acc[e]);
    float p[NE], s = 0.f;
#pragma unroll
    for (int e = 0; e < NE; ++e) { p[e] = __expf(acc[e] - m); s += p[e]; }
#pragma unroll
    for (int e = 0; e < NE; ++e) p[e] /= s;
    int i0 = 0;
#pragma unroll
    for (int e = 1; e < NE; ++e) if (p[e] > p[i0]) i0 = e;
    int i1 = (i0 == 0) ? 1 : 0;
#pragma unroll
    for (int e = 0; e < NE; ++e) if (e != i0 && p[e] > p[i1]) i1 = e;
    float w0 = p[i0], w1 = p[i1];
    float dnm = w0 + w1 + 1e-20f;
    w0 /= dnm; w1 /= dnm;
    tok_e[t * 2 + 0] = i0; tok_e[t * 2 + 1] = i1;
    tok_w[t * 2 + 0] = w0; tok_w[t * 2 + 1] = w1;
  }
}

// --------- slot assignment: single block, ballot-based stable counting sort ---------
__global__ __launch_bounds__(1024) void k_slots(const int* __restrict__ tok_e,
                                                const float* __restrict__ tok_w,
                                                int* __restrict__ rows,
                                                float* __restrict__ rw,
                                                int* __restrict__ slot_of,
                                                int* __restrict__ po_g) {
  __shared__ unsigned short rank_s[NASSIGN];
  __shared__ int chunkcnt[128][NE];
  __shared__ int po_s[NE + 1];
  __shared__ int counts_s[NE];
  int tid = threadIdx.x, lane = tid & 63, wave = tid >> 6;
  unsigned long long below = (lane == 0) ? 0ull : ((~0ull) >> (64 - lane));
#pragma unroll
  for (int j = 0; j < 8; ++j) {
    int c = wave * 8 + j;
    int a = c * 64 + lane;
    int ei = tok_e[a];
    int myrank = 0, mycnt = 0;
#pragma unroll
    for (int e = 0; e < NE; ++e) {
      unsigned long long m = __ballot(ei == e);
      if (e == ei) myrank = __popcll(m & below);
      if (lane == e) mycnt = __popcll(m);
    }
    rank_s[a] = (unsigned short)myrank;
    if (lane < NE) chunkcnt[c][lane] = mycnt;
  }
  __syncthreads();
  if (tid < NE) {
    int run = 0;
    for (int c = 0; c < 128; ++c) {
      int v = chunkcnt[c][tid];
      chunkcnt[c][tid] = run;
      run += v;
    }
    counts_s[tid] = run;
  }
  __syncthreads();
  if (tid == 0) {
    int s = 0;
    po_s[0] = 0;
    for (int e = 0; e < NE; ++e) {
      s += ((counts_s[e] + 255) >> 8) << 8;   // pad to 256
      po_s[e + 1] = s;
    }
  }
  __syncthreads();
  if (tid < NE + 1) po_g[tid] = po_s[tid];
  int po8 = po_s[NE];
#pragma unroll
  for (int j = 0; j < 8; ++j) {
    int a = tid + j * 1024;
    int e = tok_e[a];
    int c = a >> 6;
    int slot = po_s[e] + chunkcnt[c][e] + (int)rank_s[a];
    rows[slot] = a >> 1;
    rw[slot] = tok_w[a];
    slot_of[a] = slot;
  }
  // shared-expert segment: slots [po8, po8+NTOK), identity rows, weight 1
  for (int s = tid; s < NTOK; s += 1024) {
    rows[po8 + s] = s;
    rw[po8 + s] = 1.f;
  }
  // pad slots inside expert segments
  for (int s = tid; s < MAXSLOT_E; s += 1024) {
    if (s >= po8) break;
    int e = 0;
#pragma unroll
    for (int i = 1; i < NE; ++i)
      if (s >= po_s[i]) e = i;
    if (s >= po_s[e] + counts_s[e]) { rows[s] = 0; rw[s] = 0.f; }
  }
}

// ---- grouped GEMM (shared = expert 8): 256x256 tile, BK=64, 8 waves ----
// Software-pipelined phases: reads for phase p+1 issue after MFMA(p).
// Quadrant order (0,0)(0,1)(1,0)(1,1); aE/aO frag double-buffer; 1 barrier/phase.
template <bool UP>
__global__ __launch_bounds__(512, 2) void k_gemm(const unsigned short* __restrict__ A,
                                                 const unsigned short* __restrict__ Be,
                                                 const unsigned short* __restrict__ Bsh,
                                                 const float* __restrict__ be,
                                                 const float* __restrict__ bsh,
                                                 const int* __restrict__ rows,
                                                 const float* __restrict__ rw,
                                                 const int* __restrict__ po,
                                                 unsigned short* __restrict__ OutB,
                                                 float* __restrict__ OutF) {
  __shared__ unsigned short LA[2][2][128 * 64];
  __shared__ unsigned short LB[2][2][128 * 64];
  // bijective XCD-chunked swizzle (GRID_G % 8 == 0), rt-major within XCD
  int orig = blockIdx.x;
  int wgid = (orig & 7) * (GRID_G / 8) + (orig >> 3);
  int rt = wgid >> 2, ct = wgid & 3;
  int row0 = rt * 256;
  int po8 = po[NE];
  if (row0 >= po8 + NTOK) return;
  int e = NE;  // shared
  if (row0 < po8) {
    e = 0;
#pragma unroll
    for (int i = 1; i < NE; ++i)
      if (row0 >= po[i]) e = i;
  }
  const unsigned short* Bm = (e < NE) ? Be + (size_t)e * (DM * DH) : Bsh;
  const float* bia = (e < NE) ? be + (size_t)e * (UP ? DH : DM) : bsh;

  int tid = threadIdx.x, lane = tid & 63, w = tid >> 6;
  int wr = w >> 2, wc = w & 3, l15 = lane & 15;
  int s0 = (lane >> 4) ^ (lane & 7);  // kk=0 swizzled slot

  // staging: 1 load/thread/call, one 64-row quadrant; dest = uniform + lane*16B
  int st_r = tid >> 3;       // 0..63
  int st_s = tid & 7;
  int grA[2][2];
  if (UP) {
#pragma unroll
    for (int h = 0; h < 2; ++h)
#pragma unroll
      for (int q = 0; q < 2; ++q)
        grA[h][q] = rows[row0 + h * 128 + q * 64 + st_r];
  }

  f32x4 acc[8][4] = {};
  short8 aE[4][2], aO[4][2], b[4][2];

  auto STG_A = [&](int buf, int h, int q, int kt) {
    int lr = q * 64 + st_r;
    int gk = st_s ^ (lr & 7);
    int grow = UP ? grA[h][q] : (row0 + h * 128 + lr);
    async_ld16(A + (size_t)grow * 1024 + kt * 64 + gk * 8,
               &LA[buf][h][lr * 64 + st_s * 8]);
  };
  auto STG_B = [&](int buf, int h, int q, int kt) {
    int lr = q * 64 + st_r;
    int gk = st_s ^ (lr & 7);
    int gcol = ct * 256 + h * 128 + lr;
    async_ld16(Bm + (size_t)gcol * 1024 + kt * 64 + gk * 8,
               &LB[buf][h][lr * 64 + st_s * 8]);
  };

  const unsigned short* Ab_[2] = {&LA[0][wr][0], &LA[1][wr][0]};
  const unsigned short* Bb_[2] = {&LB[0][wc >> 1][0], &LB[1][wc >> 1][0]};
  int brow0 = (wc & 1) * 64 + l15;
  int sl[2] = {s0 * 8, (s0 ^ 4) * 8};

  auto RD_A = [&](int buf, int mq, short8 (*dst)[2]) {
#pragma unroll
    for (int m4 = 0; m4 < 4; ++m4)
#pragma unroll
      for (int kk = 0; kk < 2; ++kk)
        dst[m4][kk] = *(const short8*)(Ab_[buf] + (mq * 64 + m4 * 16 + l15) * 64 + sl[kk]);
  };
  auto RD_B = [&](int buf, int np) {
#pragma unroll
    for (int n2 = 0; n2 < 2; ++n2)
#pragma unroll
      for (int kk = 0; kk < 2; ++kk)
        b[np * 2 + n2][kk] =
            *(const short8*)(Bb_[buf] + (brow0 + (np * 2 + n2) * 16) * 64 + sl[kk]);
  };
  auto MFMAQ = [&](short8 (*am)[2], int mq, int np) {
    __builtin_amdgcn_s_setprio(1);
#pragma unroll
    for (int m4 = 0; m4 < 4; ++m4)
#pragma unroll
      for (int n2 = 0; n2 < 2; ++n2)
#pragma unroll
        for (int kk = 0; kk < 2; ++kk)
          acc[mq * 4 + m4][np * 2 + n2] = __builtin_amdgcn_mfma_f32_16x16x32_bf16(
              am[m4][kk], b[np * 2 + n2][kk], acc[mq * 4 + m4][np * 2 + n2], 0, 0, 0);
    __builtin_amdgcn_s_setprio(0);
    __builtin_amdgcn_sched_barrier(0);
  };

  // ---- prologue: tile0 -> buf0, tile1 -> buf1; then pre-issue ph1's frags
  STG_A(0, 0, 0, 0); STG_A(0, 1, 0, 0); STG_A(0, 0, 1, 0); STG_A(0, 1, 1, 0);
  STG_B(0, 0, 0, 0); STG_B(0, 0, 1, 0); STG_B(0, 1, 0, 0); STG_B(0, 1, 1, 0);
  STG_A(1, 0, 0, 1); STG_A(1, 1, 0, 1); STG_A(1, 0, 1, 1); STG_A(1, 1, 1, 1);
  STG_B(1, 0, 0, 1); STG_B(1, 0, 1, 1); STG_B(1, 1, 0, 1); STG_B(1, 1, 1, 1);
  VMCNT(8);  // tile0 landed; tile1 in flight
  BARR();
  RD_A(0, 0, aE); RD_B(0, 0);  // frags for ph1 of tile 0

  // ---- 8 iterations x 2 tiles x 4 phases; each phase:
  //   lgkm(0) -> MFMA(p) -> issue ds_reads(p+1) -> STG calendar -> [vmcnt] -> barrier
  // Frag lifetimes: aE live ph1-2 (refilled end-ph3), aO ph3-4 (refilled end-ph2),
  // b.np0 ph1&3 (refilled end-ph4), b.np1 ph2&4 (refilled end-ph1).
  // STG calendar (region reads lgkm-drained >=1 barrier before write issue):
  //   ph2: A-q0 x2 | ph3: B-h0 x2 | ph4: A-q1 x2 + B-h1 x2 + VMCNT(8).
  for (int it = 0; it < 8; ++it) {
    int tn = (2 * it + 2) & 15, un = (2 * it + 3) & 15;
#pragma unroll
    for (int half = 0; half < 2; ++half) {
      int bf = half, nb = half ^ 1;
      int kt = half ? un : tn;
      // ph1 (0,0)
      LGKM0(); MFMAQ(aE, 0, 0);
      RD_B(bf, 1);
      BARR();
      // ph2 (0,1)
      LGKM0(); MFMAQ(aE, 0, 1);
      RD_A(bf, 1, aO);
      STG_A(bf, 0, 0, kt); STG_A(bf, 1, 0, kt);
      BARR();
      // ph3 (1,0)
      LGKM0(); MFMAQ(aO, 1, 0);
      RD_A(nb, 0, aE);
      STG_B(bf, 0, 0, kt); STG_B(bf, 0, 1, kt);
      BARR();
      // ph4 (1,1)
      LGKM0(); MFMAQ(aO, 1, 1);
      RD_B(nb, 0);
      STG_A(bf, 0, 1, kt); STG_A(bf, 1, 1, kt);
      STG_B(bf, 1, 0, kt); STG_B(bf, 1, 1, kt);
      VMCNT(8);
      BARR();
    }
  }
  VMCNT(0);  // drain wrapped dummy stages before epilogue

  // ---- epilogue
  int gcol0 = ct * 256 + wc * 64;
#pragma unroll
  for (int m = 0; m < 8; ++m) {
    int rbase = row0 + wr * 128 + m * 16 + ((lane >> 4) << 2);
#pragma unroll
    for (int j = 0; j < 4; ++j) {
      int grow = rbase + j;
#pragma unroll
      for (int n = 0; n < 4; ++n) {
        int gc = gcol0 + n * 16 + l15;
        float v = acc[m][n][j] + bia[gc];
        if (UP) {
          v = v / (1.f + __expf(-v));  // silu
          OutB[(size_t)grow * DH + gc] = f2bf(v);
        } else if (e < NE) {
          OutB[(size_t)grow * DM + gc] = f2bf(v * rw[grow]);
        } else {
          OutF[(size_t)(grow - po8) * DM + gc] = v;  // shared -> out fp32
        }
      }
    }
  }
}

// ---------------- final combine: out[t] += YE[s0] + YE[s1] ----------------
__global__ __launch_bounds__(256) void k_combine(float* __restrict__ out,
                                                 const unsigned short* __restrict__ YE,
                                                 const int* __restrict__ slot_of) {
  int t = blockIdx.x;
  int s0 = slot_of[t * 2 + 0], s1 = slot_of[t * 2 + 1];
  int c = threadIdx.x * 4;
  float* op = out + (size_t)t * DM + c;
  float4 o = *(float4*)op;
  ushort4 a = *(const ushort4*)(YE + (size_t)s0 * DM + c);
  ushort4 b = *(const ushort4*)(YE + (size_t)s1 * DM + c);
  o.x += bf2f(a.x) + bf2f(b.x);
  o.y += bf2f(a.y) + bf2f(b.y);
  o.z += bf2f(a.z) + bf2f(b.z);
  o.w += bf2f(a.w) + bf2f(b.w);
  *(float4*)op = o;
}

extern "C" void kernel_launch(void* const* d_in, const int* in_sizes, int n_in,
                              void* d_out, int out_size, void* d_ws, size_t ws_size,
                              hipStream_t stream) {
  const float* x        = (const float*)d_in[0];
  const float* gate_w   = (const float*)d_in[1];
  const float* up_w     = (const float*)d_in[2];
  const float* up_b     = (const float*)d_in[3];
  const float* down_w   = (const float*)d_in[4];
  const float* down_b   = (const float*)d_in[5];
  const float* sh_up_w  = (const float*)d_in[6];
  const float* sh_up_b  = (const float*)d_in[7];
  const float* sh_dn_w  = (const float*)d_in[8];
  const float* sh_dn_b  = (const float*)d_in[9];
  float* out = (float*)d_out;

  char* ws = (char*)d_ws;
  const size_t MB = 1024 * 1024;
  unsigned short* xb   = (unsigned short*)(ws + 0);          // 8 MB
  unsigned short* upT  = (unsigned short*)(ws + 8 * MB);     // 16 MB
  unsigned short* dnT  = (unsigned short*)(ws + 24 * MB);    // 16 MB
  unsigned short* shuT = (unsigned short*)(ws + 40 * MB);    // 2 MB
  unsigned short* shdT = (unsigned short*)(ws + 42 * MB);    // 2 MB
  unsigned short* H    = (unsigned short*)(ws + 44 * MB);    // 28 MB
  char* tail = ws + 44 * MB + (size_t)MAXSLOT_ALL * DH * 2;
  int*   tok_e   = (int*)tail;                tail += NASSIGN * 4;
  float* tok_w   = (float*)tail;              tail += NASSIGN * 4;
  int*   slot_of = (int*)tail;                tail += NASSIGN * 4;
  int*   rows    = (int*)tail;                tail += MAXSLOT_ALL * 4;
  float* rw      = (float*)tail;              tail += MAXSLOT_ALL * 4;
  int*   po      = (int*)tail;                tail += 64;
  unsigned short* YE = (unsigned short*)(ws + 0);            // alias xb+upT

  // 1) dtype conversions / weight transposes
  k_cvt<<<(NTOK * DM) / 1024, 256, 0, stream>>>(x, xb, NTOK * DM);
  k_tcvt_all<<<dim3(16, 16, 18), 256, 0, stream>>>(up_w, down_w, sh_up_w, sh_dn_w,
                                                   upT, dnT, shuT, shdT);

  // 2) routing (no atomics)
  k_route<<<NTOK / 4, 256, 0, stream>>>(x, gate_w, tok_e, tok_w);
  k_slots<<<1, 1024, 0, stream>>>(tok_e, tok_w, rows, rw, slot_of, po);

  // 3) grouped GEMMs (experts 0..7 + shared as 8), pipelined 8-phase, XCD-swizzled
  k_gemm<true><<<GRID_G, 512, 0, stream>>>(
      xb, upT, shuT, up_b, sh_up_b, rows, rw, po, H, nullptr);
  k_gemm<false><<<GRID_G, 512, 0, stream>>>(
      H, dnT, shdT, down_b, sh_dn_b, rows, rw, po, YE, out);

  // 4) combine
  k_combine<<<NTOK, 256, 0, stream>>>(out, YE, slot_of);
}

// Round 12
// 141.159 us; speedup vs baseline: 1.1626x; 1.0855x over previous
//
#include <hip/hip_runtime.h>
#include <hip/hip_bf16.h>
#include <cstdint>
#include <cstddef>

// MoE FFN: x[2,2048,1024] fp32, 8 experts top-2 + 1 shared expert.
// R1: no-atomic routing.  R2: shared expert fused as expert #8.
// R3: LDS swizzle (conflicts 0).  R6/R8: 256x256 8-wave 8-phase, vmcnt ledger.
// R9: XCD-chunked swizzle (FETCH -> compulsory ~31MB).  R10: reg-frag pipeline.
// R11 (failed): fused route+cvt only processed 256/1024 elems per token.
// R12: k_route_cvt fixed (4-chunk loop, full row converted + gated);
//      GEMM unchanged from R11: 2 phases/K-tile, 32-MFMA clusters, 32 barriers,
//      VMCNT(8) before next-buffer frag reads.

#define NTOK 4096
#define DM 1024
#define DH 1024
#define NE 8
#define MAXSLOT_E 10240           // 8192 assignments + 8*256 padding (worst case)
#define MAXSLOT_ALL (MAXSLOT_E + NTOK)  // + shared segment (4096) = 14336
#define NASSIGN (NTOK * 2)
#define NRT2 (MAXSLOT_ALL / 256)  // 56 row tiles
#define GRID_G (NRT2 * 4)         // 224 blocks (4 col tiles), 224 % 8 == 0

typedef __attribute__((ext_vector_type(8))) short short8;
typedef __attribute__((ext_vector_type(8))) unsigned short ushort8v;
typedef __attribute__((ext_vector_type(4))) float f32x4;

__device__ __forceinline__ unsigned short f2bf(float f) {
  uint32_t u = __float_as_uint(f);
  return (unsigned short)((u + 0x7FFFu + ((u >> 16) & 1u)) >> 16);  // RNE
}
__device__ __forceinline__ float bf2f(unsigned short h) {
  return __uint_as_float(((uint32_t)h) << 16);
}

__device__ __forceinline__ void async_ld16(const void* g, void* l) {
  __builtin_amdgcn_global_load_lds(
      (const __attribute__((address_space(1))) void*)g,
      (__attribute__((address_space(3))) void*)l, 16, 0, 0);
}

__device__ __forceinline__ void BARR() {
  asm volatile("" ::: "memory");
  __builtin_amdgcn_s_barrier();
  asm volatile("" ::: "memory");
}
__device__ __forceinline__ void LGKM0() {
  asm volatile("s_waitcnt lgkmcnt(0)" ::: "memory");
  __builtin_amdgcn_sched_barrier(0);
}
#define VMCNT(n) asm volatile("s_waitcnt vmcnt(" #n ")" ::: "memory")

// --- fp32 [1024][1024] -> bf16 transposed, ALL weight matrices in one dispatch ---
__global__ __launch_bounds__(256) void k_tcvt_all(const float* __restrict__ up_w,
                                                  const float* __restrict__ down_w,
                                                  const float* __restrict__ sh_up,
                                                  const float* __restrict__ sh_dn,
                                                  unsigned short* __restrict__ upT,
                                                  unsigned short* __restrict__ dnT,
                                                  unsigned short* __restrict__ shuT,
                                                  unsigned short* __restrict__ shdT) {
  __shared__ float tile[64][65];
  int z = blockIdx.z;
  const float* S;
  unsigned short* D;
  if (z < 8)       { S = up_w   + (size_t)z * (DM * DH);       D = upT + (size_t)z * (DM * DH); }
  else if (z < 16) { S = down_w + (size_t)(z - 8) * (DM * DH); D = dnT + (size_t)(z - 8) * (DM * DH); }
  else if (z == 16){ S = sh_up;  D = shuT; }
  else             { S = sh_dn;  D = shdT; }
  int r0 = blockIdx.y * 64, c0 = blockIdx.x * 64;
  int t = threadIdx.x;
  int fc = (t & 15) * 4, rr = t >> 4;
#pragma unroll
  for (int i = 0; i < 4; ++i) {
    int r = rr + i * 16;
    float4 v = *(const float4*)&S[(size_t)(r0 + r) * 1024 + c0 + fc];
    tile[r][fc + 0] = v.x; tile[r][fc + 1] = v.y;
    tile[r][fc + 2] = v.z; tile[r][fc + 3] = v.w;
  }
  __syncthreads();
  int c = t >> 2;
  int rs = (t & 3) * 16;
#pragma unroll
  for (int j = 0; j < 2; ++j) {
    int rb = rs + j * 8;
    ushort8v o;
#pragma unroll
    for (int k = 0; k < 8; ++k) o[k] = f2bf(tile[rb + k][c]);
    *(ushort8v*)&D[(size_t)(c0 + c) * 1024 + r0 + rb] = o;
  }
}

// ------ fused: x fp32 -> xb bf16 AND gating (logits/softmax/top2/renorm) ------
// One wave per token; lane handles float4 chunks lane, lane+64, lane+128, lane+192
// (FULL 1024-elem row — R11's bug was covering only the first 256).
__global__ __launch_bounds__(256) void k_route_cvt(const float* __restrict__ x,
                                                   const float* __restrict__ gw,
                                                   unsigned short* __restrict__ xb,
                                                   int* __restrict__ tok_e,
                                                   float* __restrict__ tok_w) {
  int wave = threadIdx.x >> 6, lane = threadIdx.x & 63;
  int t = blockIdx.x * 4 + wave;
  const float4* xt = (const float4*)(x + (size_t)t * DM);
  unsigned short* xbt = xb + (size_t)t * DM;
  float acc[NE];
#pragma unroll
  for (int e = 0; e < NE; ++e) acc[e] = 0.f;
#pragma unroll
  for (int c = 0; c < 4; ++c) {
    int idx = lane + c * 64;              // float4 index 0..255
    float4 v = xt[idx];
    ushort4 o;
    o.x = f2bf(v.x); o.y = f2bf(v.y); o.z = f2bf(v.z); o.w = f2bf(v.w);
    *(ushort4*)(xbt + idx * 4) = o;
#pragma unroll
    for (int e = 0; e < NE; ++e) {
      float4 g = ((const float4*)(gw + (size_t)e * DM))[idx];
      acc[e] += v.x * g.x + v.y * g.y + v.z * g.z + v.w * g.w;
    }
  }
#pragma unroll
  for (int e = 0; e < NE; ++e) {
#pragma unroll
    for (int off = 32; off; off >>= 1) acc[e] += __shfl_xor(acc[e], off, 64);
  }
  if (lane == 0) {
    float m = acc[0];
#pragma unroll
    for (int e = 1; e < NE; ++e) m = fmaxf(m, acc[e]);
    float p[NE], s = 0.f;
#pragma unroll
    for (int e = 0; e < NE; ++e) { p[e] = __expf(acc[e] - m); s += p[e]; }
#pragma unroll
    for (int e = 0; e < NE; ++e) p[e] /= s;
    int i0 = 0;
#pragma unroll
    for (int e = 1; e < NE; ++e) if (p[e] > p[i0]) i0 = e;
    int i1 = (i0 == 0) ? 1 : 0;
#pragma unroll
    for (int e = 0; e < NE; ++e) if (e != i0 && p[e] > p[i1]) i1 = e;
    float w0 = p[i0], w1 = p[i1];
    float dnm = w0 + w1 + 1e-20f;
    w0 /= dnm; w1 /= dnm;
    tok_e[t * 2 + 0] = i0; tok_e[t * 2 + 1] = i1;
    tok_w[t * 2 + 0] = w0; tok_w[t * 2 + 1] = w1;
  }
}

// --------- slot assignment: single block, ballot-based stable counting sort ---------
__global__ __launch_bounds__(1024) void k_slots(const int* __restrict__ tok_e,
                                                const float* __restrict__ tok_w,
                                                int* __restrict__ rows,
                                                float* __restrict__ rw,
                                                int* __restrict__ slot_of,
                                                int* __restrict__ po_g) {
  __shared__ unsigned short rank_s[NASSIGN];
  __shared__ int chunkcnt[128][NE];
  __shared__ int po_s[NE + 1];
  __shared__ int counts_s[NE];
  int tid = threadIdx.x, lane = tid & 63, wave = tid >> 6;
  unsigned long long below = (lane == 0) ? 0ull : ((~0ull) >> (64 - lane));
#pragma unroll
  for (int j = 0; j < 8; ++j) {
    int c = wave * 8 + j;
    int a = c * 64 + lane;
    int ei = tok_e[a];
    int myrank = 0, mycnt = 0;
#pragma unroll
    for (int e = 0; e < NE; ++e) {
      unsigned long long m = __ballot(ei == e);
      if (e == ei) myrank = __popcll(m & below);
      if (lane == e) mycnt = __popcll(m);
    }
    rank_s[a] = (unsigned short)myrank;
    if (lane < NE) chunkcnt[c][lane] = mycnt;
  }
  __syncthreads();
  if (tid < NE) {
    int run = 0;
    for (int c = 0; c < 128; ++c) {
      int v = chunkcnt[c][tid];
      chunkcnt[c][tid] = run;
      run += v;
    }
    counts_s[tid] = run;
  }
  __syncthreads();
  if (tid == 0) {
    int s = 0;
    po_s[0] = 0;
    for (int e = 0; e < NE; ++e) {
      s += ((counts_s[e] + 255) >> 8) << 8;   // pad to 256
      po_s[e + 1] = s;
    }
  }
  __syncthreads();
  if (tid < NE + 1) po_g[tid] = po_s[tid];
  int po8 = po_s[NE];
#pragma unroll
  for (int j = 0; j < 8; ++j) {
    int a = tid + j * 1024;
    int e = tok_e[a];
    int c = a >> 6;
    int slot = po_s[e] + chunkcnt[c][e] + (int)rank_s[a];
    rows[slot] = a >> 1;
    rw[slot] = tok_w[a];
    slot_of[a] = slot;
  }
  // shared-expert segment: slots [po8, po8+NTOK), identity rows, weight 1
  for (int s = tid; s < NTOK; s += 1024) {
    rows[po8 + s] = s;
    rw[po8 + s] = 1.f;
  }
  // pad slots inside expert segments
  for (int s = tid; s < MAXSLOT_E; s += 1024) {
    if (s >= po8) break;
    int e = 0;
#pragma unroll
    for (int i = 1; i < NE; ++i)
      if (s >= po_s[i]) e = i;
    if (s >= po_s[e] + counts_s[e]) { rows[s] = 0; rw[s] = 0.f; }
  }
}

// ---- grouped GEMM (shared = expert 8): 256x256 tile, BK=64, 8 waves ----
// 2 phases / K-tile, 32-MFMA clusters, 32 barriers total; VMCNT(8) precedes
// next-buffer frag reads (ledger provably covers staging).
template <bool UP>
__global__ __launch_bounds__(512, 2) void k_gemm(const unsigned short* __restrict__ A,
                                                 const unsigned short* __restrict__ Be,
                                                 const unsigned short* __restrict__ Bsh,
                                                 const float* __restrict__ be,
                                                 const float* __restrict__ bsh,
                                                 const int* __restrict__ rows,
                                                 const float* __restrict__ rw,
                                                 const int* __restrict__ po,
                                                 unsigned short* __restrict__ OutB,
                                                 float* __restrict__ OutF) {
  __shared__ unsigned short LA[2][2][128 * 64];
  __shared__ unsigned short LB[2][2][128 * 64];
  // bijective XCD-chunked swizzle (GRID_G % 8 == 0), rt-major within XCD
  int orig = blockIdx.x;
  int wgid = (orig & 7) * (GRID_G / 8) + (orig >> 3);
  int rt = wgid >> 2, ct = wgid & 3;
  int row0 = rt * 256;
  int po8 = po[NE];
  if (row0 >= po8 + NTOK) return;
  int e = NE;  // shared
  if (row0 < po8) {
    e = 0;
#pragma unroll
    for (int i = 1; i < NE; ++i)
      if (row0 >= po[i]) e = i;
  }
  const unsigned short* Bm = (e < NE) ? Be + (size_t)e * (DM * DH) : Bsh;
  const float* bia = (e < NE) ? be + (size_t)e * (UP ? DH : DM) : bsh;

  int tid = threadIdx.x, lane = tid & 63, w = tid >> 6;
  int wr = w >> 2, wc = w & 3, l15 = lane & 15;
  int s0 = (lane >> 4) ^ (lane & 7);  // kk=0 swizzled slot

  // staging: 1 load/thread/call, one 64-row quadrant; dest = uniform + lane*16B
  int st_r = tid >> 3;       // 0..63
  int st_s = tid & 7;
  int grA[2][2];
  if (UP) {
#pragma unroll
    for (int h = 0; h < 2; ++h)
#pragma unroll
      for (int q = 0; q < 2; ++q)
        grA[h][q] = rows[row0 + h * 128 + q * 64 + st_r];
  }

  f32x4 acc[8][4] = {};
  short8 aE[4][2], aO[4][2], b[4][2];

  auto STG_A = [&](int buf, int h, int q, int kt) {
    int lr = q * 64 + st_r;
    int gk = st_s ^ (lr & 7);
    int grow = UP ? grA[h][q] : (row0 + h * 128 + lr);
    async_ld16(A + (size_t)grow * 1024 + kt * 64 + gk * 8,
               &LA[buf][h][lr * 64 + st_s * 8]);
  };
  auto STG_B = [&](int buf, int h, int q, int kt) {
    int lr = q * 64 + st_r;
    int gk = st_s ^ (lr & 7);
    int gcol = ct * 256 + h * 128 + lr;
    async_ld16(Bm + (size_t)gcol * 1024 + kt * 64 + gk * 8,
               &LB[buf][h][lr * 64 + st_s * 8]);
  };

  const unsigned short* Ab_[2] = {&LA[0][wr][0], &LA[1][wr][0]};
  const unsigned short* Bb_[2] = {&LB[0][wc >> 1][0], &LB[1][wc >> 1][0]};
  int brow0 = (wc & 1) * 64 + l15;
  int sl[2] = {s0 * 8, (s0 ^ 4) * 8};

  auto RD_A = [&](int buf, int mq, short8 (*dst)[2]) {
#pragma unroll
    for (int m4 = 0; m4 < 4; ++m4)
#pragma unroll
      for (int kk = 0; kk < 2; ++kk)
        dst[m4][kk] = *(const short8*)(Ab_[buf] + (mq * 64 + m4 * 16 + l15) * 64 + sl[kk]);
  };
  auto RD_B = [&](int buf, int np) {
#pragma unroll
    for (int n2 = 0; n2 < 2; ++n2)
#pragma unroll
      for (int kk = 0; kk < 2; ++kk)
        b[np * 2 + n2][kk] =
            *(const short8*)(Bb_[buf] + (brow0 + (np * 2 + n2) * 16) * 64 + sl[kk]);
  };
  // 32-MFMA cluster: one A row-quadrant (mq) x ALL 4 n-frags x 2 kk
  auto MFMA32 = [&](short8 (*am)[2], int mq) {
    __builtin_amdgcn_s_setprio(1);
#pragma unroll
    for (int m4 = 0; m4 < 4; ++m4)
#pragma unroll
      for (int n = 0; n < 4; ++n)
#pragma unroll
        for (int kk = 0; kk < 2; ++kk)
          acc[mq * 4 + m4][n] = __builtin_amdgcn_mfma_f32_16x16x32_bf16(
              am[m4][kk], b[n][kk], acc[mq * 4 + m4][n], 0, 0, 0);
    __builtin_amdgcn_s_setprio(0);
    __builtin_amdgcn_sched_barrier(0);
  };

  // ---- prologue: tile0 -> buf0, tile1 -> buf1; frags for tile0
  STG_A(0, 0, 0, 0); STG_A(0, 1, 0, 0); STG_A(0, 0, 1, 0); STG_A(0, 1, 1, 0);
  STG_B(0, 0, 0, 0); STG_B(0, 0, 1, 0); STG_B(0, 1, 0, 0); STG_B(0, 1, 1, 0);
  STG_A(1, 0, 0, 1); STG_A(1, 1, 0, 1); STG_A(1, 0, 1, 1); STG_A(1, 1, 1, 1);
  STG_B(1, 0, 0, 1); STG_B(1, 0, 1, 1); STG_B(1, 1, 0, 1); STG_B(1, 1, 1, 1);
  VMCNT(8);  // tile0 landed (oldest 8); tile1 in flight
  BARR();
  RD_A(0, 0, aE); RD_B(0, 0); RD_B(0, 1);  // tile0 ph1 frags

  // ---- 8 iterations x 2 tiles x 2 phases.
  // ph1: MFMA(mq0) | RD aO(bf q1) | STG bf: A-q0 x2, B-h0 x2 | BARR
  // ph2: MFMA(mq1) | STG bf: A-q1 x2, B-h1 x2 | VMCNT(8) | RD nb: aE + b | BARR
  for (int it = 0; it < 8; ++it) {
    int tn = (2 * it + 2) & 15, un = (2 * it + 3) & 15;
#pragma unroll
    for (int half = 0; half < 2; ++half) {
      int bf = half, nb = half ^ 1;
      int kt = half ? un : tn;
      // ph1
      LGKM0(); MFMA32(aE, 0);
      RD_A(bf, 1, aO);
      STG_A(bf, 0, 0, kt); STG_A(bf, 1, 0, kt);
      STG_B(bf, 0, 0, kt); STG_B(bf, 0, 1, kt);
      BARR();
      // ph2
      LGKM0(); MFMA32(aO, 1);
      STG_A(bf, 0, 1, kt); STG_A(bf, 1, 1, kt);
      STG_B(bf, 1, 0, kt); STG_B(bf, 1, 1, kt);
      VMCNT(8);  // nb's tile fully landed before its frag reads below
      RD_A(nb, 0, aE); RD_B(nb, 0); RD_B(nb, 1);
      BARR();
    }
  }
  VMCNT(0);  // drain wrapped dummy stages before epilogue

  // ---- epilogue
  int gcol0 = ct * 256 + wc * 64;
#pragma unroll
  for (int m = 0; m < 8; ++m) {
    int rbase = row0 + wr * 128 + m * 16 + ((lane >> 4) << 2);
#pragma unroll
    for (int j = 0; j < 4; ++j) {
      int grow = rbase + j;
#pragma unroll
      for (int n = 0; n < 4; ++n) {
        int gc = gcol0 + n * 16 + l15;
        float v = acc[m][n][j] + bia[gc];
        if (UP) {
          v = v / (1.f + __expf(-v));  // silu
          OutB[(size_t)grow * DH + gc] = f2bf(v);
        } else if (e < NE) {
          OutB[(size_t)grow * DM + gc] = f2bf(v * rw[grow]);
        } else {
          OutF[(size_t)(grow - po8) * DM + gc] = v;  // shared -> out fp32
        }
      }
    }
  }
}

// ---------------- final combine: out[t] += YE[s0] + YE[s1] ----------------
__global__ __launch_bounds__(256) void k_combine(float* __restrict__ out,
                                                 const unsigned short* __restrict__ YE,
                                                 const int* __restrict__ slot_of) {
  int t = blockIdx.x;
  int s0 = slot_of[t * 2 + 0], s1 = slot_of[t * 2 + 1];
  int c = threadIdx.x * 4;
  float* op = out + (size_t)t * DM + c;
  float4 o = *(float4*)op;
  ushort4 a = *(const ushort4*)(YE + (size_t)s0 * DM + c);
  ushort4 b = *(const ushort4*)(YE + (size_t)s1 * DM + c);
  o.x += bf2f(a.x) + bf2f(b.x);
  o.y += bf2f(a.y) + bf2f(b.y);
  o.z += bf2f(a.z) + bf2f(b.z);
  o.w += bf2f(a.w) + bf2f(b.w);
  *(float4*)op = o;
}

extern "C" void kernel_launch(void* const* d_in, const int* in_sizes, int n_in,
                              void* d_out, int out_size, void* d_ws, size_t ws_size,
                              hipStream_t stream) {
  const float* x        = (const float*)d_in[0];
  const float* gate_w   = (const float*)d_in[1];
  const float* up_w     = (const float*)d_in[2];
  const float* up_b     = (const float*)d_in[3];
  const float* down_w   = (const float*)d_in[4];
  const float* down_b   = (const float*)d_in[5];
  const float* sh_up_w  = (const float*)d_in[6];
  const float* sh_up_b  = (const float*)d_in[7];
  const float* sh_dn_w  = (const float*)d_in[8];
  const float* sh_dn_b  = (const float*)d_in[9];
  float* out = (float*)d_out;

  char* ws = (char*)d_ws;
  const size_t MB = 1024 * 1024;
  unsigned short* xb   = (unsigned short*)(ws + 0);          // 8 MB
  unsigned short* upT  = (unsigned short*)(ws + 8 * MB);     // 16 MB
  unsigned short* dnT  = (unsigned short*)(ws + 24 * MB);    // 16 MB
  unsigned short* shuT = (unsigned short*)(ws + 40 * MB);    // 2 MB
  unsigned short* shdT = (unsigned short*)(ws + 42 * MB);    // 2 MB
  unsigned short* H    = (unsigned short*)(ws + 44 * MB);    // 28 MB
  char* tail = ws + 44 * MB + (size_t)MAXSLOT_ALL * DH * 2;
  int*   tok_e   = (int*)tail;                tail += NASSIGN * 4;
  float* tok_w   = (float*)tail;              tail += NASSIGN * 4;
  int*   slot_of = (int*)tail;                tail += NASSIGN * 4;
  int*   rows    = (int*)tail;                tail += MAXSLOT_ALL * 4;
  float* rw      = (float*)tail;              tail += MAXSLOT_ALL * 4;
  int*   po      = (int*)tail;                tail += 64;
  unsigned short* YE = (unsigned short*)(ws + 0);            // alias xb+upT

  // 1) weight transposes (one dispatch) + fused x-convert/route
  k_tcvt_all<<<dim3(16, 16, 18), 256, 0, stream>>>(up_w, down_w, sh_up_w, sh_dn_w,
                                                   upT, dnT, shuT, shdT);
  k_route_cvt<<<NTOK / 4, 256, 0, stream>>>(x, gate_w, xb, tok_e, tok_w);
  k_slots<<<1, 1024, 0, stream>>>(tok_e, tok_w, rows, rw, slot_of, po);

  // 2) grouped GEMMs (experts 0..7 + shared as 8), 2-phase 32-MFMA clusters
  k_gemm<true><<<GRID_G, 512, 0, stream>>>(
      xb, upT, shuT, up_b, sh_up_b, rows, rw, po, H, nullptr);
  k_gemm<false><<<GRID_G, 512, 0, stream>>>(
      H, dnT, shdT, down_b, sh_dn_b, rows, rw, po, YE, out);

  // 3) combine
  k_combine<<<NTOK, 256, 0, stream>>>(out, YE, slot_of);
}